// Round 3
// baseline (2511.103 us; speedup 1.0000x reference)
//
#include <hip/hip_runtime.h>
#include <hip/hip_fp16.h>

#define N_IND 1000000
#define N_ORG 300000
#define N_EXT 100000
#define F 64
#define E_PER 1000000
#define NREL 14

#define BW 512            // bucket width in nodes
#define NB_IND 1954       // ceil(N_IND/BW)
#define NB_ORG 586        // ceil(N_ORG/BW)
#define CAP_IND 3968      // mean 3584 + 6.4 sigma
#define CAP_ORG 12608     // mean 11947 + 6.1 sigma

// ---- workspace layout (in 4-byte words) ----
static const size_t OFF_PAY_IND  = 0;                          // u32[NB_IND][CAP_IND] = 7,753,472
static const size_t OFF_PAY_ORG  = 7753472;                    // u32[NB_ORG][CAP_ORG] = 7,388,288
static const size_t OFF_CUR      = 15141760;                   // u32[NB_IND+NB_ORG]=2540 (pad 2560)
static const size_t OFF_P_IND    = 15144320;                   // f32[5][N_IND]
static const size_t OFF_P_ORG    = 20144320;                   // f32[5][N_ORG]
static const size_t OFF_P_EXT    = 21644320;                   // f32[4][N_EXT]
static const size_t OFF_BASE_IND = 22044320;                   // f32[N_IND]
static const size_t OFF_BASE_ORG = 23044320;                   // f32[N_ORG]
static const size_t OFF_WM_IND   = 23344320;                   // 6*64
static const size_t OFF_WM_ORG   = 23344704;                   // 6*64
static const size_t OFF_WM_EXT   = 23345088;                   // 4*64
static const size_t OFF_BSUM     = 23345344;                   // 2
// total ~23.35M words = 93.4 MB

// Build packed weight matrices + combined Wr/b per dst type.
__global__ void prep_kernel(const float* __restrict__ Wl,
                            const float* __restrict__ Wr,
                            const float* __restrict__ b,
                            float* __restrict__ wm_ind,
                            float* __restrict__ wm_org,
                            float* __restrict__ wm_ext,
                            float* __restrict__ bsum) {
    int t = threadIdx.x; // 64 threads
    const int ind_wl[5] = {0, 3, 6, 7, 10};   // rels with src=ind (p_ind slots 0..4)
    const int org_wl[5] = {1, 4, 8, 11, 13};  // src=org
    const int ext_wl[4] = {2, 5, 9, 12};      // src=ext
    const int ind_r[7]  = {0, 1, 2, 7, 8, 9, 13};   // rels with dst=ind
    const int org_r[7]  = {3, 4, 5, 6, 10, 11, 12}; // dst=org
#pragma unroll
    for (int k = 0; k < 5; ++k) wm_ind[k * 64 + t] = Wl[ind_wl[k] * 64 + t];
#pragma unroll
    for (int k = 0; k < 5; ++k) wm_org[k * 64 + t] = Wl[org_wl[k] * 64 + t];
#pragma unroll
    for (int k = 0; k < 4; ++k) wm_ext[k * 64 + t] = Wl[ext_wl[k] * 64 + t];
    float si = 0.f, so = 0.f;
#pragma unroll
    for (int k = 0; k < 7; ++k) {
        si += Wr[ind_r[k] * 64 + t];
        so += Wr[org_r[k] * 64 + t];
    }
    wm_ind[5 * 64 + t] = si;
    wm_org[5 * 64 + t] = so;
    if (t == 0) {
        float bi = 0.f, bo = 0.f;
#pragma unroll
        for (int k = 0; k < 7; ++k) { bi += b[ind_r[k]]; bo += b[org_r[k]]; }
        bsum[0] = bi;
        bsum[1] = bo;
    }
}

// Per-node rank-1 projections: K dots per node. If HASBASE, last dot is the
// combined Wr projection -> base_out (+bsum).
template <int K, bool HASBASE>
__global__ __launch_bounds__(256) void proj_kernel(
    const float* __restrict__ x, int n,
    const float* __restrict__ wm,
    float* __restrict__ p,            // [K or K-1][n]
    float* __restrict__ base_out,     // null if !HASBASE
    const float* __restrict__ bsum) {
    int i = blockIdx.x * 256 + threadIdx.x;
    if (i >= n) return;
    const float4* xv = (const float4*)(x + (size_t)i * F);
    float acc[K];
#pragma unroll
    for (int k = 0; k < K; ++k) acc[k] = 0.f;
#pragma unroll
    for (int c = 0; c < 16; ++c) {
        float4 v = xv[c];
#pragma unroll
        for (int k = 0; k < K; ++k) {
            const float* w = wm + k * 64 + c * 4;
            acc[k] += v.x * w[0] + v.y * w[1] + v.z * w[2] + v.w * w[3];
        }
    }
    constexpr int NP = HASBASE ? K - 1 : K;
#pragma unroll
    for (int k = 0; k < NP; ++k) p[(size_t)k * n + i] = acc[k];
    if (HASBASE) base_out[i] = acc[K - 1] + bsum[0];
}

// Phase 1: bin edges by dst bucket. One u32 cursor atomic per edge; payload
// word = fp16(pv)<<16 | slot<<9 | dst_local. Payload writes are dense
// (cursor-sequenced) within each bucket.
__global__ __launch_bounds__(256) void scatter_kernel(
    const int* __restrict__ ei, // [14][2][E]
    const float* __restrict__ p_ind,
    const float* __restrict__ p_org,
    const float* __restrict__ p_ext,
    unsigned int* __restrict__ cursors,   // [NB_IND + NB_ORG]
    unsigned int* __restrict__ pay_ind,   // [NB_IND][CAP_IND]
    unsigned int* __restrict__ pay_org) { // [NB_ORG][CAP_ORG]
    const int r = blockIdx.y;
    const int e = blockIdx.x * 256 + threadIdx.x;
    if (e >= E_PER) return;
    const int srcType[NREL] = {0,1,2,0,1,2,0,0,1,2,0,1,2,1};
    const int srcSlot[NREL] = {0,0,0,1,1,1,2,3,2,2,4,3,3,4};
    const int dstType[NREL] = {0,0,0,1,1,1,1,0,0,0,1,1,1,0};
    const int dstSlot[NREL] = {0,1,2,0,1,2,3,3,4,5,4,5,6,6};

    const int src = ei[((size_t)r * 2 + 0) * E_PER + e];
    const int dst = ei[((size_t)r * 2 + 1) * E_PER + e];

    float pv;
    const int st = srcType[r];
    if (st == 0)      pv = p_ind[(size_t)srcSlot[r] * N_IND + src];
    else if (st == 1) pv = p_org[(size_t)srcSlot[r] * N_ORG + src];
    else              pv = p_ext[(size_t)srcSlot[r] * N_EXT + src];

    __half hh = __float2half_rn(pv);
    unsigned short hs;
    __builtin_memcpy(&hs, &hh, 2);
    unsigned int word = ((unsigned int)hs << 16) |
                        ((unsigned int)dstSlot[r] << 9) |
                        (unsigned int)(dst & (BW - 1));
    const int bkt = dst >> 9;
    if (dstType[r] == 0) {
        unsigned pos = atomicAdd(&cursors[bkt], 1u);
        if (pos < CAP_IND) pay_ind[(size_t)bkt * CAP_IND + pos] = word;
    } else {
        unsigned pos = atomicAdd(&cursors[NB_IND + bkt], 1u);
        if (pos < CAP_ORG) pay_org[(size_t)bkt * CAP_ORG + pos] = word;
    }
}

// Phase 2: one block per bucket. LDS (sum,cnt) accumulate, then fused
// finalize: out = sigmoid(base + sum_slots mean).
__global__ __launch_bounds__(256) void gather_kernel(
    const unsigned int* __restrict__ pay_ind,
    const unsigned int* __restrict__ pay_org,
    const unsigned int* __restrict__ cursors,
    const float* __restrict__ base_ind,
    const float* __restrict__ base_org,
    float* __restrict__ out) {
    __shared__ float s[7 * BW];
    __shared__ unsigned int c[7 * BW];
    const int blk = blockIdx.x;
    const bool isInd = blk < NB_IND;
    const int b = isInd ? blk : blk - NB_IND;
    for (int i = threadIdx.x; i < 7 * BW; i += 256) { s[i] = 0.f; c[i] = 0u; }
    __syncthreads();
    const unsigned int* pay = isInd ? (pay_ind + (size_t)b * CAP_IND)
                                    : (pay_org + (size_t)b * CAP_ORG);
    const unsigned cap = isInd ? CAP_IND : CAP_ORG;
    unsigned cnt = cursors[isInd ? b : NB_IND + b];
    if (cnt > cap) cnt = cap;
    for (unsigned e = threadIdx.x; e < cnt; e += 256) {
        unsigned w = pay[e];
        unsigned short hs = (unsigned short)(w >> 16);
        __half hh;
        __builtin_memcpy(&hh, &hs, 2);
        float pv = __half2float(hh);
        int idx = (int)((w >> 9) & 7u) * BW + (int)(w & (BW - 1));
        atomicAdd(&s[idx], pv);
        atomicAdd(&c[idx], 1u);
    }
    __syncthreads();
    const int n = isInd ? N_IND : N_ORG;
    const float* basep = isInd ? base_ind : base_org;
    float* outp = isInd ? out : out + N_IND;
    for (int loc = threadIdx.x; loc < BW; loc += 256) {
        int g = b * BW + loc;
        if (g < n) {
            float acc = basep[g];
#pragma unroll
            for (int k = 0; k < 7; ++k)
                acc += s[k * BW + loc] / fmaxf((float)c[k * BW + loc], 1.0f);
            outp[g] = 1.0f / (1.0f + __expf(-acc));
        }
    }
}

extern "C" void kernel_launch(void* const* d_in, const int* in_sizes, int n_in,
                              void* d_out, int out_size, void* d_ws, size_t ws_size,
                              hipStream_t stream) {
    const float* x_ind = (const float*)d_in[0];
    const float* x_org = (const float*)d_in[1];
    const float* x_ext = (const float*)d_in[2];
    const float* Wl    = (const float*)d_in[3];
    const float* Wr    = (const float*)d_in[4];
    const float* b     = (const float*)d_in[5];
    const int*   ei    = (const int*)d_in[6];
    float* out = (float*)d_out;

    float* ws = (float*)d_ws;
    unsigned int* pay_ind = (unsigned int*)(ws + OFF_PAY_IND);
    unsigned int* pay_org = (unsigned int*)(ws + OFF_PAY_ORG);
    unsigned int* cursors = (unsigned int*)(ws + OFF_CUR);
    float* p_ind    = ws + OFF_P_IND;
    float* p_org    = ws + OFF_P_ORG;
    float* p_ext    = ws + OFF_P_EXT;
    float* base_ind = ws + OFF_BASE_IND;
    float* base_org = ws + OFF_BASE_ORG;
    float* wm_ind   = ws + OFF_WM_IND;
    float* wm_org   = ws + OFF_WM_ORG;
    float* wm_ext   = ws + OFF_WM_EXT;
    float* bsum     = ws + OFF_BSUM;

    // zero only the cursors (10 KB)
    hipMemsetAsync(cursors, 0, (NB_IND + NB_ORG) * sizeof(unsigned int), stream);

    prep_kernel<<<1, 64, 0, stream>>>(Wl, Wr, b, wm_ind, wm_org, wm_ext, bsum);

    proj_kernel<6, true><<<(N_IND + 255) / 256, 256, 0, stream>>>(
        x_ind, N_IND, wm_ind, p_ind, base_ind, bsum + 0);
    proj_kernel<6, true><<<(N_ORG + 255) / 256, 256, 0, stream>>>(
        x_org, N_ORG, wm_org, p_org, base_org, bsum + 1);
    proj_kernel<4, false><<<(N_EXT + 255) / 256, 256, 0, stream>>>(
        x_ext, N_EXT, wm_ext, p_ext, nullptr, bsum);

    dim3 egrid((E_PER + 255) / 256, NREL);
    scatter_kernel<<<egrid, 256, 0, stream>>>(ei, p_ind, p_org, p_ext,
                                              cursors, pay_ind, pay_org);

    gather_kernel<<<NB_IND + NB_ORG, 256, 0, stream>>>(
        pay_ind, pay_org, cursors, base_ind, base_org, out);
}

// Round 4
// 700.700 us; speedup vs baseline: 3.5837x; 3.5837x over previous
//
#include <hip/hip_runtime.h>
#include <hip/hip_fp16.h>

#define N_IND 1000000
#define N_ORG 300000
#define N_EXT 100000
#define F 64
#define E_PER 1000000
#define NREL 14

#define BW 512            // bucket width in nodes
#define NB_IND 1954       // ceil(N_IND/BW)
#define NB_ORG 586        // ceil(N_ORG/BW)
#define NBKT 2560         // padded total bucket count (2540 used)
#define CAP_IND 3968
#define CAP_ORG 12608
#define NCHK 64           // chunks per relation
#define CHUNK 15625       // E_PER / NCHK
#define NCH_TOT (NCHK * NREL) // 896

#define FIX_SCALE 262144.0f            // 2^18
#define FIX_INV   3.814697265625e-6f   // 2^-18

// ---- workspace layout (in 4-byte words) ----
static const size_t OFF_PAY_IND  = 0;              // u32[NB_IND][CAP_IND] = 7,753,472
static const size_t OFF_PAY_ORG  = 7753472;        // u32[NB_ORG][CAP_ORG] = 7,388,288
static const size_t OFF_HIST     = 15141760;       // u32[896][2560] = 2,293,760
static const size_t OFF_CNTS     = 17435520;       // u32[2560]
static const size_t OFF_P_IND    = 17438080;       // f32[5][N_IND]
static const size_t OFF_P_ORG    = 22438080;       // f32[5][N_ORG]
static const size_t OFF_P_EXT    = 23938080;       // f32[4][N_EXT]
static const size_t OFF_BASE_IND = 24338080;       // f32[N_IND]
static const size_t OFF_BASE_ORG = 25338080;       // f32[N_ORG]
static const size_t OFF_WM_IND   = 25638080;       // 6*64
static const size_t OFF_WM_ORG   = 25638464;       // 6*64
static const size_t OFF_WM_EXT   = 25638848;       // 4*64
static const size_t OFF_BSUM     = 25639104;       // 2
// total 25,639,106 words = 102.6 MB (<= 105.6 MB proven available)

__global__ void prep_kernel(const float* __restrict__ Wl,
                            const float* __restrict__ Wr,
                            const float* __restrict__ b,
                            float* __restrict__ wm_ind,
                            float* __restrict__ wm_org,
                            float* __restrict__ wm_ext,
                            float* __restrict__ bsum) {
    int t = threadIdx.x; // 64 threads
    const int ind_wl[5] = {0, 3, 6, 7, 10};
    const int org_wl[5] = {1, 4, 8, 11, 13};
    const int ext_wl[4] = {2, 5, 9, 12};
    const int ind_r[7]  = {0, 1, 2, 7, 8, 9, 13};
    const int org_r[7]  = {3, 4, 5, 6, 10, 11, 12};
#pragma unroll
    for (int k = 0; k < 5; ++k) wm_ind[k * 64 + t] = Wl[ind_wl[k] * 64 + t];
#pragma unroll
    for (int k = 0; k < 5; ++k) wm_org[k * 64 + t] = Wl[org_wl[k] * 64 + t];
#pragma unroll
    for (int k = 0; k < 4; ++k) wm_ext[k * 64 + t] = Wl[ext_wl[k] * 64 + t];
    float si = 0.f, so = 0.f;
#pragma unroll
    for (int k = 0; k < 7; ++k) {
        si += Wr[ind_r[k] * 64 + t];
        so += Wr[org_r[k] * 64 + t];
    }
    wm_ind[5 * 64 + t] = si;
    wm_org[5 * 64 + t] = so;
    if (t == 0) {
        float bi = 0.f, bo = 0.f;
#pragma unroll
        for (int k = 0; k < 7; ++k) { bi += b[ind_r[k]]; bo += b[org_r[k]]; }
        bsum[0] = bi;
        bsum[1] = bo;
    }
}

template <int K, bool HASBASE>
__global__ __launch_bounds__(256) void proj_kernel(
    const float* __restrict__ x, int n,
    const float* __restrict__ wm,
    float* __restrict__ p,
    float* __restrict__ base_out,
    const float* __restrict__ bsum) {
    int i = blockIdx.x * 256 + threadIdx.x;
    if (i >= n) return;
    const float4* xv = (const float4*)(x + (size_t)i * F);
    float acc[K];
#pragma unroll
    for (int k = 0; k < K; ++k) acc[k] = 0.f;
#pragma unroll
    for (int c = 0; c < 16; ++c) {
        float4 v = xv[c];
#pragma unroll
        for (int k = 0; k < K; ++k) {
            const float* w = wm + k * 64 + c * 4;
            acc[k] += v.x * w[0] + v.y * w[1] + v.z * w[2] + v.w * w[3];
        }
    }
    constexpr int NP = HASBASE ? K - 1 : K;
#pragma unroll
    for (int k = 0; k < NP; ++k) p[(size_t)k * n + i] = acc[k];
    if (HASBASE) base_out[i] = acc[K - 1] + bsum[0];
}

// Pass 1: per-(chunk, relation) LDS histogram over dst buckets.
__global__ __launch_bounds__(256) void hist_kernel(
    const int* __restrict__ ei, unsigned* __restrict__ hist) {
    const int r = blockIdx.y, ci = blockIdx.x;
    const int dstType[NREL] = {0,0,0,1,1,1,1,0,0,0,1,1,1,0};
    __shared__ unsigned h[NBKT];
    for (int i = threadIdx.x; i < NBKT; i += 256) h[i] = 0u;
    __syncthreads();
    const int* dstp = ei + ((size_t)r * 2 + 1) * E_PER + (size_t)ci * CHUNK;
    const int boff = dstType[r] ? NB_IND : 0;
    for (int k = threadIdx.x; k < CHUNK; k += 256) {
        int dst = dstp[k];
        atomicAdd(&h[boff + (dst >> 9)], 1u);
    }
    __syncthreads();
    unsigned* hc = hist + (size_t)(r * NCHK + ci) * NBKT;
    for (int i = threadIdx.x; i < NBKT; i += 256) hc[i] = h[i];
}

// Pass 2: per-bucket exclusive prefix over chunks (in place) + totals.
__global__ __launch_bounds__(256) void scan_kernel(
    unsigned* __restrict__ hist, unsigned* __restrict__ cnts) {
    int b = blockIdx.x * 256 + threadIdx.x; // 0..2559
    unsigned run = 0;
#pragma unroll 4
    for (int c = 0; c < NCH_TOT; ++c) {
        size_t idx = (size_t)c * NBKT + b;
        unsigned v = hist[idx];
        hist[idx] = run;
        run += v;
    }
    cnts[b] = run;
}

// Pass 3: deterministic scatter. LDS cursors seeded from the scanned hist;
// payload word = fp16(pv)<<16 | slot<<9 | dst_local.
__global__ __launch_bounds__(256) void scatter_kernel(
    const int* __restrict__ ei,
    const float* __restrict__ p_ind,
    const float* __restrict__ p_org,
    const float* __restrict__ p_ext,
    const unsigned* __restrict__ hist,
    unsigned* __restrict__ pay_ind,
    unsigned* __restrict__ pay_org) {
    const int r = blockIdx.y, ci = blockIdx.x;
    const int srcType[NREL] = {0,1,2,0,1,2,0,0,1,2,0,1,2,1};
    const int srcSlot[NREL] = {0,0,0,1,1,1,2,3,2,2,4,3,3,4};
    const int dstType[NREL] = {0,0,0,1,1,1,1,0,0,0,1,1,1,0};
    const int dstSlot[NREL] = {0,1,2,0,1,2,3,3,4,5,4,5,6,6};
    __shared__ unsigned o[NBKT];
    const unsigned* hc = hist + (size_t)(r * NCHK + ci) * NBKT;
    for (int i = threadIdx.x; i < NBKT; i += 256) o[i] = hc[i];
    __syncthreads();

    const int st = srcType[r];
    const float* psrc = (st == 0) ? p_ind + (size_t)srcSlot[r] * N_IND
                      : (st == 1) ? p_org + (size_t)srcSlot[r] * N_ORG
                                  : p_ext + (size_t)srcSlot[r] * N_EXT;
    const int* srcp = ei + ((size_t)r * 2 + 0) * E_PER + (size_t)ci * CHUNK;
    const int* dstp = ei + ((size_t)r * 2 + 1) * E_PER + (size_t)ci * CHUNK;
    const int isOrg = dstType[r];
    const unsigned slotbits = (unsigned)dstSlot[r] << 9;

    for (int k = threadIdx.x; k < CHUNK; k += 256) {
        int src = srcp[k];
        int dst = dstp[k];
        float pv = psrc[src];
        __half hh = __float2half_rn(pv);
        unsigned short hs;
        __builtin_memcpy(&hs, &hh, 2);
        unsigned word = ((unsigned)hs << 16) | slotbits | (unsigned)(dst & (BW - 1));
        int fb = dst >> 9;
        if (!isOrg) {
            unsigned pos = atomicAdd(&o[fb], 1u);
            if (pos < CAP_IND) pay_ind[(size_t)fb * CAP_IND + pos] = word;
        } else {
            unsigned pos = atomicAdd(&o[NB_IND + fb], 1u);
            if (pos < CAP_ORG) pay_org[(size_t)fb * CAP_ORG + pos] = word;
        }
    }
}

// Pass 4: one block per bucket; packed u32 LDS accumulate (cnt<<26 | s26
// fixed-point sum), fused finalize + sigmoid.
__global__ __launch_bounds__(256) void gather_kernel(
    const unsigned* __restrict__ pay_ind,
    const unsigned* __restrict__ pay_org,
    const unsigned* __restrict__ cnts,
    const float* __restrict__ base_ind,
    const float* __restrict__ base_org,
    float* __restrict__ out) {
    __shared__ unsigned acc[7 * BW];
    const int blk = blockIdx.x;
    const bool isInd = blk < NB_IND;
    const int b = isInd ? blk : blk - NB_IND;
    for (int i = threadIdx.x; i < 7 * BW; i += 256) acc[i] = 0u;
    __syncthreads();
    const unsigned* pay = isInd ? (pay_ind + (size_t)b * CAP_IND)
                                : (pay_org + (size_t)b * CAP_ORG);
    const unsigned cap = isInd ? CAP_IND : CAP_ORG;
    unsigned cnt = cnts[blk];
    if (cnt > cap) cnt = cap;
    for (unsigned e = threadIdx.x; e < cnt; e += 256) {
        unsigned w = pay[e];
        unsigned short hs = (unsigned short)(w >> 16);
        __half hh;
        __builtin_memcpy(&hh, &hs, 2);
        float pv = __half2float(hh);
        int fixed = (int)rintf(pv * FIX_SCALE);
        unsigned contrib = (1u << 26) + (unsigned)fixed;
        int idx = (int)((w >> 9) & 7u) * BW + (int)(w & (BW - 1));
        atomicAdd(&acc[idx], contrib);
    }
    __syncthreads();
    const int n = isInd ? N_IND : N_ORG;
    const float* basep = isInd ? base_ind : base_org;
    float* outp = isInd ? out : out + N_IND;
    for (int loc = threadIdx.x; loc < BW; loc += 256) {
        int g = b * BW + loc;
        if (g < n) {
            float a = basep[g];
#pragma unroll
            for (int k = 0; k < 7; ++k) {
                unsigned w = acc[k * BW + loc];
                int s26 = ((int)(w << 6)) >> 6;            // sign-extend low 26
                unsigned c = (w - (unsigned)s26) >> 26;    // exact count
                a += (float)s26 * FIX_INV / fmaxf((float)c, 1.0f);
            }
            outp[g] = 1.0f / (1.0f + __expf(-a));
        }
    }
}

extern "C" void kernel_launch(void* const* d_in, const int* in_sizes, int n_in,
                              void* d_out, int out_size, void* d_ws, size_t ws_size,
                              hipStream_t stream) {
    const float* x_ind = (const float*)d_in[0];
    const float* x_org = (const float*)d_in[1];
    const float* x_ext = (const float*)d_in[2];
    const float* Wl    = (const float*)d_in[3];
    const float* Wr    = (const float*)d_in[4];
    const float* b     = (const float*)d_in[5];
    const int*   ei    = (const int*)d_in[6];
    float* out = (float*)d_out;

    float* ws = (float*)d_ws;
    unsigned* pay_ind = (unsigned*)(ws + OFF_PAY_IND);
    unsigned* pay_org = (unsigned*)(ws + OFF_PAY_ORG);
    unsigned* hist    = (unsigned*)(ws + OFF_HIST);
    unsigned* cnts    = (unsigned*)(ws + OFF_CNTS);
    float* p_ind    = ws + OFF_P_IND;
    float* p_org    = ws + OFF_P_ORG;
    float* p_ext    = ws + OFF_P_EXT;
    float* base_ind = ws + OFF_BASE_IND;
    float* base_org = ws + OFF_BASE_ORG;
    float* wm_ind   = ws + OFF_WM_IND;
    float* wm_org   = ws + OFF_WM_ORG;
    float* wm_ext   = ws + OFF_WM_EXT;
    float* bsum     = ws + OFF_BSUM;

    prep_kernel<<<1, 64, 0, stream>>>(Wl, Wr, b, wm_ind, wm_org, wm_ext, bsum);

    proj_kernel<6, true><<<(N_IND + 255) / 256, 256, 0, stream>>>(
        x_ind, N_IND, wm_ind, p_ind, base_ind, bsum + 0);
    proj_kernel<6, true><<<(N_ORG + 255) / 256, 256, 0, stream>>>(
        x_org, N_ORG, wm_org, p_org, base_org, bsum + 1);
    proj_kernel<4, false><<<(N_EXT + 255) / 256, 256, 0, stream>>>(
        x_ext, N_EXT, wm_ext, p_ext, nullptr, bsum);

    dim3 cgrid(NCHK, NREL);
    hist_kernel<<<cgrid, 256, 0, stream>>>(ei, hist);
    scan_kernel<<<NBKT / 256, 256, 0, stream>>>(hist, cnts);
    scatter_kernel<<<cgrid, 256, 0, stream>>>(ei, p_ind, p_org, p_ext,
                                              hist, pay_ind, pay_org);
    gather_kernel<<<NB_IND + NB_ORG, 256, 0, stream>>>(
        pay_ind, pay_org, cnts, base_ind, base_org, out);
}

// Round 5
// 341.690 us; speedup vs baseline: 7.3491x; 2.0507x over previous
//
#include <hip/hip_runtime.h>
#include <hip/hip_fp16.h>

#define N_IND 1000000
#define N_ORG 300000
#define N_EXT 100000
#define F 64
#define E_PER 1000000
#define NREL 14

#define BW 1024                 // bucket width (nodes)
#define NB_IND 977              // ceil(N_IND/BW)
#define NB_ORG 293              // ceil(N_ORG/BW)
#define NBKT 1270               // used buckets
#define NBKT_PAD 1280           // padded (5 per thread at 256 thr)
#define CHUNK 8192              // edges per column
#define COLS_PER_REL 123        // ceil(E_PER/CHUNK)
#define NCOL (NREL * COLS_PER_REL) // 1722
#define LAST_N (E_PER - (COLS_PER_REL - 1) * CHUNK) // 576
#define NBLK_SCAT 512

#define FIX_SCALE 262144.0f            // 2^18
#define FIX_INV   3.814697265625e-6f   // 2^-18

// ---- workspace layout (in 4-byte words) ----
static const size_t OFF_PAY      = 0;          // u32[NCOL][CHUNK] = 14,106,624
static const size_t OFF_CNTOFF   = 14106624;   // u32[NCOL][NBKT_PAD] = 2,204,160
static const size_t OFF_CNTOFF_T = 16310784;   // u32[NBKT_PAD][NCOL] = 2,204,160
static const size_t OFF_P_IND    = 18514944;   // fp16[5][N_IND]  = 2,500,000 words
static const size_t OFF_P_ORG    = 21014944;   // fp16[5][N_ORG]  =   750,000
static const size_t OFF_P_EXT    = 21764944;   // fp16[4][N_EXT]  =   200,000
static const size_t OFF_BASE_IND = 21964944;   // f32[N_IND]
static const size_t OFF_BASE_ORG = 22964944;   // f32[N_ORG]
static const size_t OFF_WM_IND   = 23264944;   // 6*64
static const size_t OFF_WM_ORG   = 23265328;   // 6*64
static const size_t OFF_WM_EXT   = 23265712;   // 4*64
static const size_t OFF_BSUM     = 23265968;   // 2
// total 23,265,970 words = 93.1 MB

__global__ void prep_kernel(const float* __restrict__ Wl,
                            const float* __restrict__ Wr,
                            const float* __restrict__ b,
                            float* __restrict__ wm_ind,
                            float* __restrict__ wm_org,
                            float* __restrict__ wm_ext,
                            float* __restrict__ bsum) {
    int t = threadIdx.x; // 64 threads
    const int ind_wl[5] = {0, 3, 6, 7, 10};
    const int org_wl[5] = {1, 4, 8, 11, 13};
    const int ext_wl[4] = {2, 5, 9, 12};
    const int ind_r[7]  = {0, 1, 2, 7, 8, 9, 13};
    const int org_r[7]  = {3, 4, 5, 6, 10, 11, 12};
#pragma unroll
    for (int k = 0; k < 5; ++k) wm_ind[k * 64 + t] = Wl[ind_wl[k] * 64 + t];
#pragma unroll
    for (int k = 0; k < 5; ++k) wm_org[k * 64 + t] = Wl[org_wl[k] * 64 + t];
#pragma unroll
    for (int k = 0; k < 4; ++k) wm_ext[k * 64 + t] = Wl[ext_wl[k] * 64 + t];
    float si = 0.f, so = 0.f;
#pragma unroll
    for (int k = 0; k < 7; ++k) {
        si += Wr[ind_r[k] * 64 + t];
        so += Wr[org_r[k] * 64 + t];
    }
    wm_ind[5 * 64 + t] = si;
    wm_org[5 * 64 + t] = so;
    if (t == 0) {
        float bi = 0.f, bo = 0.f;
#pragma unroll
        for (int k = 0; k < 7; ++k) { bi += b[ind_r[k]]; bo += b[org_r[k]]; }
        bsum[0] = bi;
        bsum[1] = bo;
    }
}

// Rank-1 projections -> fp16 p slices (+ f32 base for dst types).
template <int K, bool HASBASE>
__global__ __launch_bounds__(256) void proj_kernel(
    const float* __restrict__ x, int n,
    const float* __restrict__ wm,
    __half* __restrict__ p,           // [K or K-1][n] fp16
    float* __restrict__ base_out,
    const float* __restrict__ bsum) {
    int i = blockIdx.x * 256 + threadIdx.x;
    if (i >= n) return;
    const float4* xv = (const float4*)(x + (size_t)i * F);
    float acc[K];
#pragma unroll
    for (int k = 0; k < K; ++k) acc[k] = 0.f;
#pragma unroll
    for (int c = 0; c < 16; ++c) {
        float4 v = xv[c];
#pragma unroll
        for (int k = 0; k < K; ++k) {
            const float* w = wm + k * 64 + c * 4;
            acc[k] += v.x * w[0] + v.y * w[1] + v.z * w[2] + v.w * w[3];
        }
    }
    constexpr int NP = HASBASE ? K - 1 : K;
#pragma unroll
    for (int k = 0; k < NP; ++k) p[(size_t)k * n + i] = __float2half_rn(acc[k]);
    if (HASBASE) base_out[i] = acc[K - 1] + bsum[0];
}

// Persistent scatter: 512 blocks walk columns (rel-major -> L2-resident fp16
// slice). Per column: LDS histogram -> LDS exclusive scan -> LDS-staged local
// sort -> dense 32 KB stream-out + packed (off<<16|cnt) table row.
__global__ __launch_bounds__(256) void scatter_kernel(
    const int* __restrict__ ei,
    const unsigned short* __restrict__ p_ind,
    const unsigned short* __restrict__ p_org,
    const unsigned short* __restrict__ p_ext,
    unsigned* __restrict__ pay,      // [NCOL][CHUNK]
    unsigned* __restrict__ cntoff) { // [NCOL][NBKT_PAD]
    const int srcType[NREL] = {0,1,2,0,1,2,0,0,1,2,0,1,2,1};
    const int srcSlot[NREL] = {0,0,0,1,1,1,2,3,2,2,4,3,3,4};
    const int dstType[NREL] = {0,0,0,1,1,1,1,0,0,0,1,1,1,0};
    const int dstSlot[NREL] = {0,1,2,0,1,2,3,3,4,5,4,5,6,6};

    __shared__ unsigned h[NBKT_PAD];
    __shared__ unsigned cur[NBKT_PAD];
    __shared__ unsigned part[256];
    __shared__ unsigned stage[CHUNK];

    const int t = threadIdx.x;
    for (int cid = blockIdx.x; cid < NCOL; cid += NBLK_SCAT) {
        const int r = cid / COLS_PER_REL;
        const int i = cid - r * COLS_PER_REL;
        const int n = (i == COLS_PER_REL - 1) ? LAST_N : CHUNK;
        const int* srcp = ei + ((size_t)r * 2 + 0) * E_PER + (size_t)i * CHUNK;
        const int* dstp = ei + ((size_t)r * 2 + 1) * E_PER + (size_t)i * CHUNK;
        const int boff = dstType[r] ? NB_IND : 0;
        const unsigned slotbits = (unsigned)dstSlot[r] << 10;
        const int st = srcType[r];
        const unsigned short* psrc =
            (st == 0) ? p_ind + (size_t)srcSlot[r] * N_IND :
            (st == 1) ? p_org + (size_t)srcSlot[r] * N_ORG :
                        p_ext + (size_t)srcSlot[r] * N_EXT;

        // pass 1: histogram
#pragma unroll
        for (int j = 0; j < 5; ++j) h[t * 5 + j] = 0u;
        __syncthreads();
        for (int k = t; k < n; k += 256)
            atomicAdd(&h[boff + (dstp[k] >> 10)], 1u);
        __syncthreads();

        // local exclusive scan over 1280 counters (5/thread + block scan)
        unsigned loc[5], s0 = 0;
#pragma unroll
        for (int j = 0; j < 5; ++j) { loc[j] = h[t * 5 + j]; s0 += loc[j]; }
        part[t] = s0;
        __syncthreads();
        for (int d = 1; d < 256; d <<= 1) {
            unsigned v = (t >= d) ? part[t - d] : 0u;
            __syncthreads();
            part[t] += v;
            __syncthreads();
        }
        unsigned base = part[t] - s0;
        unsigned* co = cntoff + (size_t)cid * NBKT_PAD;
#pragma unroll
        for (int j = 0; j < 5; ++j) {
            co[t * 5 + j] = (base << 16) | loc[j];
            cur[t * 5 + j] = base;
            base += loc[j];
        }
        __syncthreads();

        // pass 2: place into LDS stage at sorted positions
        for (int k = t; k < n; k += 256) {
            int src = srcp[k];
            int dst = dstp[k];
            unsigned pvbits = psrc[src];
            unsigned word = (pvbits << 16) | slotbits | (unsigned)(dst & (BW - 1));
            unsigned pos = atomicAdd(&cur[boff + (dst >> 10)], 1u);
            stage[pos] = word;
        }
        __syncthreads();

        // dense stream-out
        unsigned* payc = pay + (size_t)cid * CHUNK;
        for (int k = t; k < n; k += 256) payc[k] = stage[k];
        __syncthreads();
    }
}

// Transpose cntoff [NCOL][NBKT_PAD] -> [NBKT_PAD][NCOL] (32x32 tiles).
__global__ __launch_bounds__(256) void transpose_kernel(
    const unsigned* __restrict__ in, unsigned* __restrict__ out) {
    __shared__ unsigned tb[32][33];
    const int c0 = blockIdx.x * 32; // col in 'in' (bucket)
    const int r0 = blockIdx.y * 32; // row in 'in' (cid)
    const int tx = threadIdx.x & 31, ty = threadIdx.x >> 5; // ty 0..7
#pragma unroll
    for (int j = 0; j < 32; j += 8) {
        int r = r0 + ty + j, c = c0 + tx;
        if (r < NCOL && c < NBKT_PAD) tb[ty + j][tx] = in[(size_t)r * NBKT_PAD + c];
    }
    __syncthreads();
#pragma unroll
    for (int j = 0; j < 32; j += 8) {
        int r = c0 + ty + j, c = r0 + tx;
        if (r < NBKT_PAD && c < NCOL) out[(size_t)r * NCOL + c] = tb[tx][ty + j];
    }
}

// One block per bucket: walk all columns' (off,cnt), read dense payload
// segments, packed fixed-point LDS accumulate, fused finalize + sigmoid.
__global__ __launch_bounds__(256) void gather_kernel(
    const unsigned* __restrict__ pay,
    const unsigned* __restrict__ cntoffT,
    const float* __restrict__ base_ind,
    const float* __restrict__ base_org,
    float* __restrict__ out) {
    __shared__ unsigned acc[7 * BW];
    const int blk = blockIdx.x; // 0..NBKT-1 (ind: 0..976, org: 977..1269)
    const int t = threadIdx.x;
    for (int j = t; j < 7 * BW; j += 256) acc[j] = 0u;
    __syncthreads();

    const unsigned* row = cntoffT + (size_t)blk * NCOL;
    for (int cid = t; cid < NCOL; cid += 256) {
        unsigned co = row[cid];
        unsigned cnt = co & 0xffffu;
        if (!cnt) continue;
        const unsigned* seg = pay + (size_t)cid * CHUNK + (co >> 16);
        for (unsigned e = 0; e < cnt; ++e) {
            unsigned w = seg[e];
            unsigned short hs = (unsigned short)(w >> 16);
            __half hh;
            __builtin_memcpy(&hh, &hs, 2);
            float pv = __half2float(hh);
            int fixed = (int)rintf(pv * FIX_SCALE);
            unsigned contrib = (1u << 26) + (unsigned)fixed;
            atomicAdd(&acc[((w >> 10) & 7u) * BW + (w & (BW - 1))], contrib);
        }
    }
    __syncthreads();

    const bool isInd = blk < NB_IND;
    const int b = isInd ? blk : blk - NB_IND;
    const int nn = isInd ? N_IND : N_ORG;
    const float* basep = isInd ? base_ind : base_org;
    float* outp = isInd ? out : out + N_IND;
    for (int loc = t; loc < BW; loc += 256) {
        int g = b * BW + loc;
        if (g < nn) {
            float a = basep[g];
#pragma unroll
            for (int k = 0; k < 7; ++k) {
                unsigned w = acc[k * BW + loc];
                int s26 = ((int)(w << 6)) >> 6;         // sign-extend low 26
                unsigned c = (w - (unsigned)s26) >> 26; // exact count
                a += (float)s26 * FIX_INV / fmaxf((float)c, 1.0f);
            }
            outp[g] = 1.0f / (1.0f + __expf(-a));
        }
    }
}

extern "C" void kernel_launch(void* const* d_in, const int* in_sizes, int n_in,
                              void* d_out, int out_size, void* d_ws, size_t ws_size,
                              hipStream_t stream) {
    const float* x_ind = (const float*)d_in[0];
    const float* x_org = (const float*)d_in[1];
    const float* x_ext = (const float*)d_in[2];
    const float* Wl    = (const float*)d_in[3];
    const float* Wr    = (const float*)d_in[4];
    const float* b     = (const float*)d_in[5];
    const int*   ei    = (const int*)d_in[6];
    float* out = (float*)d_out;

    float* ws = (float*)d_ws;
    unsigned* pay      = (unsigned*)(ws + OFF_PAY);
    unsigned* cntoff   = (unsigned*)(ws + OFF_CNTOFF);
    unsigned* cntoffT  = (unsigned*)(ws + OFF_CNTOFF_T);
    __half* p_ind      = (__half*)(ws + OFF_P_IND);
    __half* p_org      = (__half*)(ws + OFF_P_ORG);
    __half* p_ext      = (__half*)(ws + OFF_P_EXT);
    float* base_ind    = ws + OFF_BASE_IND;
    float* base_org    = ws + OFF_BASE_ORG;
    float* wm_ind      = ws + OFF_WM_IND;
    float* wm_org      = ws + OFF_WM_ORG;
    float* wm_ext      = ws + OFF_WM_EXT;
    float* bsum        = ws + OFF_BSUM;

    prep_kernel<<<1, 64, 0, stream>>>(Wl, Wr, b, wm_ind, wm_org, wm_ext, bsum);

    proj_kernel<6, true><<<(N_IND + 255) / 256, 256, 0, stream>>>(
        x_ind, N_IND, wm_ind, p_ind, base_ind, bsum + 0);
    proj_kernel<6, true><<<(N_ORG + 255) / 256, 256, 0, stream>>>(
        x_org, N_ORG, wm_org, p_org, base_org, bsum + 1);
    proj_kernel<4, false><<<(N_EXT + 255) / 256, 256, 0, stream>>>(
        x_ext, N_EXT, wm_ext, p_ext, nullptr, bsum);

    scatter_kernel<<<NBLK_SCAT, 256, 0, stream>>>(
        ei, (const unsigned short*)p_ind, (const unsigned short*)p_org,
        (const unsigned short*)p_ext, pay, cntoff);

    dim3 tgrid((NBKT_PAD + 31) / 32, (NCOL + 31) / 32);
    transpose_kernel<<<tgrid, 256, 0, stream>>>(cntoff, cntoffT);

    gather_kernel<<<NBKT, 256, 0, stream>>>(pay, cntoffT, base_ind, base_org, out);
}